// Round 9
// baseline (141.673 us; speedup 1.0000x reference)
//
#include <hip/hip_runtime.h>

// Problem constants (reference: N=4, L=2048, H=16, D=32, DIM=512)
#define NB      4
#define L_SEQ   2048
#define H_HEADS 16
#define D32     32
#define DIM     512
#define NH      (NB * H_HEADS)   // 64
#define CHUNK   64
#define NCHUNK  (L_SEQ / CHUNK)  // 32

typedef __attribute__((ext_vector_type(8))) short bf16x8;
typedef __attribute__((ext_vector_type(4))) float f32x4;

// f32 -> bf16 round-to-nearest-even (inputs are finite normals)
__device__ __forceinline__ unsigned short f2bf(float x) {
    unsigned u = __float_as_uint(x);
    u += 0x7fff + ((u >> 16) & 1);
    return (unsigned short)(u >> 16);
}
__device__ __forceinline__ unsigned pack2(float lo, float hi) {
    return (unsigned)f2bf(lo) | ((unsigned)f2bf(hi) << 16);
}

// ---------------------------------------------------------------------------
// Kernel 0: f32 -> bf16 conversion of query, key, Wq, Wk, Wv into one
// contiguous bf16 region (same order). 8 elements/thread, exact cover.
// ---------------------------------------------------------------------------
#define QN  4194304           // query elems
#define WN  262144            // one weight matrix
#define TOT (2*QN + 3*WN)     // 9,175,040
__global__ __launch_bounds__(256) void convert_kernel(
    const float* __restrict__ query, const float* __restrict__ key,
    const float* __restrict__ Wq, const float* __restrict__ Wk,
    const float* __restrict__ Wv, unsigned short* __restrict__ dst)
{
    int idx = (blockIdx.x * 256 + threadIdx.x) * 8;
    const float* src; int off;
    if (idx < QN)               { src = query; off = idx; }
    else if (idx < 2*QN)        { src = key;   off = idx - QN; }
    else if (idx < 2*QN + WN)   { src = Wq;    off = idx - 2*QN; }
    else if (idx < 2*QN + 2*WN) { src = Wk;    off = idx - 2*QN - WN; }
    else                        { src = Wv;    off = idx - 2*QN - 2*WN; }
    float4 a = *(const float4*)(src + off);
    float4 b = *(const float4*)(src + off + 4);
    *(uint4*)(dst + idx) = make_uint4(pack2(a.x, a.y), pack2(a.z, a.w),
                                      pack2(b.x, b.y), pack2(b.z, b.w));
}

// ---------------------------------------------------------------------------
// Kernel 1: three GEMMs via bf16 MFMA, LDS-staged, fused over blockIdx.z.
//   z=0: C[l][dout] = query @ Wq^T -> softmax(heads) -> Qs [nh][l][d]
//   z=1: C[l][dout] = key   @ Wk^T -> softmax(heads) -> Ks [nh][l][d]
//   z=2: C[dout][l] = Wv @ key^T   -> Vt [nh][d][l]   (transposed compute)
// LDS: fragment-chunk rows padded to 5 uint4 (40 shorts); both staging
// ds_write_b128 and fragment ds_read_b128 spread evenly over bank groups.
// XCD swizzle: bx = lin>>6 (col tile), by = lin&63 (row tile).
// ---------------------------------------------------------------------------
__global__ __launch_bounds__(256) void gemm3_mfma_kernel(
    const unsigned short* __restrict__ qb, const unsigned short* __restrict__ kb2,
    const unsigned short* __restrict__ wqb, const unsigned short* __restrict__ wkb,
    const unsigned short* __restrict__ wvb,
    unsigned short* __restrict__ Qs, unsigned short* __restrict__ Ks,
    unsigned short* __restrict__ Vt)
{
    const int z  = blockIdx.z;
    const int bx = blockIdx.x >> 6;      // 0..3  (128-col tile)
    const int by = blockIdx.x & 63;      // 0..63 (128-row tile)
    const unsigned short *PA, *PB;   // PA rows = output rows(m), PB rows = cols(n)
    int m0, n0;
    if (z == 0)      { PA = qb;  PB = wqb; m0 = by*128; n0 = bx*128; }
    else if (z == 1) { PA = kb2; PB = wkb; m0 = by*128; n0 = bx*128; }
    else             { PA = wvb; PB = kb2; m0 = bx*128; n0 = by*128; }

    __shared__ unsigned short Asm[128 * 40];   // 10 KB (5 uint4/row, padded)
    __shared__ unsigned short Bsm[128 * 40];   // 10 KB

    const int t    = threadIdx.x;
    const int w    = t >> 6;
    const int lane = t & 63;
    const int wm   = w >> 1, wn = w & 1;
    // fragment chunk offset (shorts): row lm at stride 40, k-chunk quad
    const int chunkoff = (lane & 15) * 40 + (lane >> 4) * 8;

    f32x4 acc[4][4] = {};

    for (int kb = 0; kb < DIM; kb += 32) {
        // stage A,B tiles: chunks li = t, t+256 per tile; pure 16B copies
        #pragma unroll
        for (int rep = 0; rep < 2; rep++) {
            int li  = t + rep * 256;
            int row = li >> 2, kq = li & 3;
            uint4 av = *(const uint4*)(PA + (size_t)(m0 + row) * DIM + kb + kq * 8);
            uint4 bv = *(const uint4*)(PB + (size_t)(n0 + row) * DIM + kb + kq * 8);
            ((uint4*)Asm)[row * 5 + kq] = av;
            ((uint4*)Bsm)[row * 5 + kq] = bv;
        }
        __syncthreads();

        bf16x8 af[4], bfr[4];
        #pragma unroll
        for (int i = 0; i < 4; i++)
            af[i] = *(const bf16x8*)(Asm + (wm * 4 + i) * 640 + chunkoff);
        #pragma unroll
        for (int j = 0; j < 4; j++)
            bfr[j] = *(const bf16x8*)(Bsm + (wn * 4 + j) * 640 + chunkoff);
        #pragma unroll
        for (int i = 0; i < 4; i++)
            #pragma unroll
            for (int j = 0; j < 4; j++)
                acc[i][j] = __builtin_amdgcn_mfma_f32_16x16x32_bf16(
                    af[i], bfr[j], acc[i][j], 0, 0, 0);
        __syncthreads();
    }

    // fused softmax over D=32 head groups along cols (Q and K only)
    if (z < 2) {
        #pragma unroll
        for (int i = 0; i < 4; i++)
            #pragma unroll
            for (int jp = 0; jp < 2; jp++)
                #pragma unroll
                for (int r = 0; r < 4; r++) {
                    float a = acc[i][2 * jp][r], b = acc[i][2 * jp + 1][r];
                    float m = fmaxf(a, b);
                    #pragma unroll
                    for (int off = 1; off < 16; off <<= 1)
                        m = fmaxf(m, __shfl_xor(m, off, 64));
                    float ea = __expf(a - m), eb = __expf(b - m);
                    float s = ea + eb;
                    #pragma unroll
                    for (int off = 1; off < 16; off <<= 1)
                        s += __shfl_xor(s, off, 64);
                    float inv = 1.0f / s;
                    acc[i][2 * jp][r]     = ea * inv;
                    acc[i][2 * jp + 1][r] = eb * inv;
                }
    }

    // epilogue: C frag row = m0+wm*64+i*16+quad*4+r, col = n0+wn*64+j*16+lm
    const int quad = lane >> 4, lm = lane & 15;
    #pragma unroll
    for (int i = 0; i < 4; i++) {
        int rbase = m0 + wm * 64 + i * 16 + quad * 4;
        #pragma unroll
        for (int r = 0; r < 4; r++) {
            int rg = rbase + r;
            #pragma unroll
            for (int j = 0; j < 4; j++) {
                int cg = n0 + wn * 64 + j * 16 + lm;
                unsigned short val = f2bf(acc[i][j][r]);
                if (z < 2) {
                    int n = rg >> 11, l = rg & 2047;
                    int h = cg >> 5,  e = cg & 31;
                    unsigned short* dp = (z == 0) ? Qs : Ks;
                    dp[(((size_t)(n * H_HEADS + h)) * L_SEQ + l) * D32 + e] = val;
                } else {
                    int h = rg >> 5,  e = rg & 31;     // rows are dout
                    int n = cg >> 11, l = cg & 2047;   // cols are l
                    Vt[(((size_t)(n * H_HEADS + h)) * D32 + e) * L_SEQ + l] = val;
                }
            }
        }
    }
}

// ---------------------------------------------------------------------------
// Kernel 2: per-chunk KV sums via MFMA — TWO CHUNKS PER WAVE (64-thr blocks).
//   ckvT[e][d] = sum_l V[l][e] * K[l][d]
// Two independent chunk pipelines per wave -> 2x ILP. 1024 blocks.
// ---------------------------------------------------------------------------
__global__ __launch_bounds__(64) void chunk_kv_mfma_kernel(
    const unsigned short* __restrict__ Ks, const unsigned short* __restrict__ Vt,
    float* __restrict__ ckvT)
{
    const int c0 = blockIdx.x * 2, nh = blockIdx.y;
    const int lane = threadIdx.x;
    const int lm = lane & 15, quad = lane >> 4;

    __shared__ unsigned short Kl[2][64 * 36];   // 9 KB

    // stage: lane loads its row (64B contiguous) of each chunk -> padded rows
    #pragma unroll
    for (int cc = 0; cc < 2; cc++) {
        const unsigned short* kg = Ks + ((size_t)nh * L_SEQ + (c0 + cc) * CHUNK + lane) * D32;
        #pragma unroll
        for (int i = 0; i < 4; i++) {
            uint4 v = *(const uint4*)(kg + i * 8);
            *(uint4*)(&Kl[cc][lane * 36 + i * 8]) = v;
        }
    }
    __syncthreads();   // single wave: orders LDS writes before reads

    f32x4 acc[2][2][2] = {};
    #pragma unroll
    for (int cc = 0; cc < 2; cc++) {
        #pragma unroll
        for (int ch = 0; ch < 2; ch++) {
            bf16x8 aV[2], bK[2];
            #pragma unroll
            for (int mt = 0; mt < 2; mt++)
                aV[mt] = *(const bf16x8*)(Vt + ((size_t)nh * D32 + mt * 16 + lm) * L_SEQ
                                             + (c0 + cc) * CHUNK + ch * 32 + quad * 8);
            #pragma unroll
            for (int nt = 0; nt < 2; nt++) {
                const unsigned short* kp = &Kl[cc][(ch * 32 + quad * 8) * 36 + nt * 16 + lm];
                #pragma unroll
                for (int j = 0; j < 8; j++) bK[nt][j] = (short)kp[j * 36];
            }
            #pragma unroll
            for (int mt = 0; mt < 2; mt++)
                #pragma unroll
                for (int nt = 0; nt < 2; nt++)
                    acc[cc][mt][nt] = __builtin_amdgcn_mfma_f32_16x16x32_bf16(
                        aV[mt], bK[nt], acc[cc][mt][nt], 0, 0, 0);
        }
    }
    #pragma unroll
    for (int cc = 0; cc < 2; cc++)
        #pragma unroll
        for (int mt = 0; mt < 2; mt++)
            #pragma unroll
            for (int nt = 0; nt < 2; nt++)
                #pragma unroll
                for (int r = 0; r < 4; r++) {
                    int e = mt * 16 + quad * 4 + r;
                    int d = nt * 16 + lm;
                    ckvT[(((size_t)nh * NCHUNK + c0 + cc) * 32 + e) * 32 + d] =
                        acc[cc][mt][nt][r];
                }
}

// ---------------------------------------------------------------------------
// Kernel 3: exclusive prefix over 32 chunks; reads ckvT f32, writes SpT bf16.
// Grid (4, NH), 64 threads: block handles 64 of the 256 float4 slots.
// ---------------------------------------------------------------------------
__global__ __launch_bounds__(64) void prefix_kernel(
    const float* __restrict__ ckvT, unsigned short* __restrict__ SpT)
{
    int nh   = blockIdx.y;
    int slot = blockIdx.x * 64 + threadIdx.x;   // 0..255
    const float* base = ckvT + (size_t)nh * NCHUNK * 1024 + slot * 4;
    unsigned short* sp = SpT + (size_t)nh * NCHUNK * 1024 + slot * 4;
    float4 acc = make_float4(0.f, 0.f, 0.f, 0.f);
    #pragma unroll
    for (int cb = 0; cb < NCHUNK; cb += 8) {
        float4 v[8];
        #pragma unroll
        for (int j = 0; j < 8; j++)
            v[j] = *(const float4*)(base + (size_t)(cb + j) * 1024);
        #pragma unroll
        for (int j = 0; j < 8; j++) {
            ushort4 u;
            u.x = f2bf(acc.x); u.y = f2bf(acc.y);
            u.z = f2bf(acc.z); u.w = f2bf(acc.w);
            *(ushort4*)(sp + (size_t)(cb + j) * 1024) = u;
            acc.x += v[j].x; acc.y += v[j].y;
            acc.z += v[j].z; acc.w += v[j].w;
        }
    }
}

// ---------------------------------------------------------------------------
// Kernel 4: per-chunk output via MFMA — TWO CHUNKS PER WAVE (64-thr blocks).
//   P = tril(Qc Kc^T) (bf16, private LDS);  O = Qc·SpT^T + P·Vt^T
// P row stride 72 shorts: holds all 64 cols (NB: stride must be >= 64 —
// stride 40 in R8 corrupted rows), and b128 aP reads spread evenly over
// bank groups (9 chunks/row, 9 coprime 8). 1024 blocks.
// ---------------------------------------------------------------------------
__global__ __launch_bounds__(64) void chunk_out_mfma_kernel(
    const unsigned short* __restrict__ Qs, const unsigned short* __restrict__ Ks,
    const unsigned short* __restrict__ Vt, const unsigned short* __restrict__ SpT,
    float* __restrict__ out)
{
    const int c0 = blockIdx.x * 2, nh = blockIdx.y;
    __shared__ unsigned short P[2][64 * 72];   // 18 KB

    const int lane = threadIdx.x;
    const int lm = lane & 15, quad = lane >> 4;

    // A-frags of Q for both chunks (kept live through phase B)
    bf16x8 aQ[2][4];
    #pragma unroll
    for (int cc = 0; cc < 2; cc++)
        #pragma unroll
        for (int i = 0; i < 4; i++)
            aQ[cc][i] = *(const bf16x8*)(Qs + ((size_t)nh * L_SEQ + (c0 + cc) * CHUNK
                                               + i * 16 + lm) * D32 + quad * 8);

    // Phase A: P[i][j] tiles for both chunks; upper (j>i) zero-filled
    #pragma unroll
    for (int cc = 0; cc < 2; cc++) {
        bf16x8 bK[4];
        #pragma unroll
        for (int j = 0; j < 4; j++)
            bK[j] = *(const bf16x8*)(Ks + ((size_t)nh * L_SEQ + (c0 + cc) * CHUNK
                                           + j * 16 + lm) * D32 + quad * 8);
        #pragma unroll
        for (int i = 0; i < 4; i++) {
            #pragma unroll
            for (int j = 0; j < 4; j++) {
                f32x4 p = {};
                if (j <= i) {
                    p = __builtin_amdgcn_mfma_f32_16x16x32_bf16(aQ[cc][i], bK[j], p, 0, 0, 0);
                    if (j == i) {
                        #pragma unroll
                        for (int r = 0; r < 4; r++)
                            if (lm > quad * 4 + r) p[r] = 0.f;   // causal: keep l' <= l
                    }
                }
                #pragma unroll
                for (int r = 0; r < 4; r++)
                    P[cc][(i * 16 + quad * 4 + r) * 72 + j * 16 + lm] = f2bf(p[r]);
            }
        }
    }
    __syncthreads();   // single wave: orders LDS writes before reads

    const int n = nh >> 4, h = nh & 15;
    #pragma unroll
    for (int cc = 0; cc < 2; cc++) {
        // phase-B global frags for this chunk
        bf16x8 bS[2], bV[2][2];
        #pragma unroll
        for (int nt = 0; nt < 2; nt++) {
            bS[nt] = *(const bf16x8*)(SpT + (((size_t)nh * NCHUNK + c0 + cc) * 32
                                             + nt * 16 + lm) * 32 + quad * 8);
            #pragma unroll
            for (int ch = 0; ch < 2; ch++)
                bV[nt][ch] = *(const bf16x8*)(Vt + ((size_t)nh * D32 + nt * 16 + lm) * L_SEQ
                                                 + (c0 + cc) * CHUNK + ch * 32 + quad * 8);
        }
        #pragma unroll
        for (int i = 0; i < 4; i++) {
            const int chmax = (i >> 1) + 1;   // lp tiles needed: i<2 -> 1, else 2
            bf16x8 aP[2];
            for (int ch = 0; ch < chmax; ch++)
                aP[ch] = *(const bf16x8*)&P[cc][(i * 16 + lm) * 72 + ch * 32 + quad * 8];
            #pragma unroll
            for (int nt = 0; nt < 2; nt++) {
                f32x4 acc = {};
                acc = __builtin_amdgcn_mfma_f32_16x16x32_bf16(aQ[cc][i], bS[nt], acc, 0, 0, 0);
                for (int ch = 0; ch < chmax; ch++)
                    acc = __builtin_amdgcn_mfma_f32_16x16x32_bf16(aP[ch], bV[nt][ch], acc, 0, 0, 0);
                #pragma unroll
                for (int r = 0; r < 4; r++) {
                    int lg = (c0 + cc) * CHUNK + i * 16 + quad * 4 + r;
                    out[((size_t)n * L_SEQ + lg) * DIM + h * D32 + nt * 16 + lm] = acc[r];
                }
            }
        }
    }
}

// ---------------------------------------------------------------------------
extern "C" void kernel_launch(void* const* d_in, const int* in_sizes, int n_in,
                              void* d_out, int out_size, void* d_ws, size_t ws_size,
                              hipStream_t stream)
{
    (void)in_sizes; (void)n_in; (void)out_size; (void)ws_size;
    const float* query = (const float*)d_in[0];
    const float* key   = (const float*)d_in[1];
    const float* Wq    = (const float*)d_in[2];
    const float* Wk    = (const float*)d_in[3];
    const float* Wv    = (const float*)d_in[4];
    float* out = (float*)d_out;

    // ws layout (bf16 shorts unless noted):
    //  [qb 4.19M][kb 4.19M][wqb 256K][wkb 256K][wvb 256K]
    //  [Qs 4.19M][Ks 4.19M][Vt 4.19M][SpT 2.10M][ckvT f32 2.10M]  ~= 56 MB
    unsigned short* bf = (unsigned short*)d_ws;
    unsigned short* qb  = bf;
    unsigned short* kb  = qb + QN;
    unsigned short* wqb = kb + QN;
    unsigned short* wkb = wqb + WN;
    unsigned short* wvb = wkb + WN;
    unsigned short* Qs  = wvb + WN;
    const size_t SZ = (size_t)NH * L_SEQ * D32;
    unsigned short* Ks  = Qs + SZ;
    unsigned short* Vt  = Ks + SZ;
    unsigned short* SpT = Vt + SZ;
    float* ckvT = (float*)(SpT + (size_t)NH * NCHUNK * 1024);

    convert_kernel<<<dim3(TOT / (256 * 8)), dim3(256), 0, stream>>>(
        query, key, Wq, Wk, Wv, qb);
    gemm3_mfma_kernel<<<dim3(256, 1, 3), dim3(256), 0, stream>>>(
        qb, kb, wqb, wkb, wvb, Qs, Ks, Vt);
    chunk_kv_mfma_kernel<<<dim3(NCHUNK / 2, NH), dim3(64), 0, stream>>>(Ks, Vt, ckvT);
    prefix_kernel<<<dim3(4, NH), dim3(64), 0, stream>>>(ckvT, SpT);
    chunk_out_mfma_kernel<<<dim3(NCHUNK / 2, NH), dim3(64), 0, stream>>>(Qs, Ks, Vt, SpT, out);
}